// Round 1
// baseline (353.960 us; speedup 1.0000x reference)
//
#include <hip/hip_runtime.h>

#define TW 32
#define TH 32
#define HALO 5
#define IW (TW + 2*HALO)   // 42
#define IH (TH + 2*HALO)   // 42
#define WS 11
#define NPLANES 96
#define IMG 512

__global__ __launch_bounds__(256) void ssim_main(const float* __restrict__ img1,
                                                 const float* __restrict__ img2,
                                                 double* __restrict__ acc) {
    __shared__ float s1[IH*IW];
    __shared__ float s2[IH*IW];
    __shared__ float hA[5][IH*TW];

    const int tid = threadIdx.x;
    const int plane = blockIdx.z;
    const int tx0 = blockIdx.x * TW - HALO;
    const int ty0 = blockIdx.y * TH - HALO;
    const float* p1 = img1 + (size_t)plane * IMG * IMG;
    const float* p2 = img2 + (size_t)plane * IMG * IMG;

    // Gaussian window weights (match jnp float32 computation within rounding)
    float w[WS];
    {
        float s = 0.f;
        #pragma unroll
        for (int i = 0; i < WS; ++i) {
            float c = (float)(i - HALO) * (1.0f/1.5f);
            w[i] = expf(-0.5f * c * c);
            s += w[i];
        }
        float inv = 1.0f / s;
        #pragma unroll
        for (int i = 0; i < WS; ++i) w[i] *= inv;
    }

    // Stage input tiles (with halo, zero-padded at image border) into LDS
    for (int i = tid; i < IH*IW; i += 256) {
        int r = i / IW, c = i - r*IW;
        int gy = ty0 + r, gx = tx0 + c;
        bool ok = (gy >= 0) & (gy < IMG) & (gx >= 0) & (gx < IMG);
        int gidx = gy * IMG + gx;
        s1[i] = ok ? p1[gidx] : 0.f;
        s2[i] = ok ? p2[gidx] : 0.f;
    }
    __syncthreads();

    // Horizontal Gaussian pass for the 5 signals
    for (int i = tid; i < IH*TW; i += 256) {
        int r = i >> 5;        // TW == 32
        int c = i & 31;
        const float* r1 = s1 + r*IW + c;
        const float* r2 = s2 + r*IW + c;
        float a1=0.f, a2=0.f, a11=0.f, a22=0.f, a12=0.f;
        #pragma unroll
        for (int k = 0; k < WS; ++k) {
            float x1 = r1[k], x2 = r2[k];
            a1  += w[k]*x1;
            a2  += w[k]*x2;
            a11 += w[k]*x1*x1;
            a22 += w[k]*x2*x2;
            a12 += w[k]*x1*x2;
        }
        hA[0][i]=a1; hA[1][i]=a2; hA[2][i]=a11; hA[3][i]=a22; hA[4][i]=a12;
    }
    __syncthreads();

    // Vertical Gaussian pass + SSIM map + local accumulation
    const float C1 = 0.01f*0.01f, C2 = 0.03f*0.03f;
    float lsum = 0.f;
    const int c  = tid & 31;
    const int r0 = tid >> 5;   // 0..7
    #pragma unroll
    for (int j = 0; j < TH/8; ++j) {
        int r = r0 + j*8;
        float mu1=0.f, mu2=0.f, m11=0.f, m22=0.f, m12=0.f;
        #pragma unroll
        for (int k = 0; k < WS; ++k) {
            int off = (r + k)*TW + c;
            mu1 += w[k]*hA[0][off];
            mu2 += w[k]*hA[1][off];
            m11 += w[k]*hA[2][off];
            m22 += w[k]*hA[3][off];
            m12 += w[k]*hA[4][off];
        }
        float mu1s = mu1*mu1, mu2s = mu2*mu2, mu12 = mu1*mu2;
        float s11 = m11 - mu1s;
        float s22 = m22 - mu2s;
        float s12 = m12 - mu12;
        float num = (2.f*mu12 + C1) * (2.f*s12 + C2);
        float den = (mu1s + mu2s + C1) * (s11 + s22 + C2);
        lsum += num / den;
    }

    // Wave (64-lane) shuffle reduce, then block reduce, one atomic per block
    #pragma unroll
    for (int d = 32; d >= 1; d >>= 1)
        lsum += __shfl_down(lsum, d, 64);
    __shared__ float wsum[4];
    if ((tid & 63) == 0) wsum[tid >> 6] = lsum;
    __syncthreads();
    if (tid == 0) {
        float t = wsum[0] + wsum[1] + wsum[2] + wsum[3];
        atomicAdd(acc, (double)t);
    }
}

__global__ void ssim_final(const double* __restrict__ acc, float* __restrict__ out) {
    out[0] = 1.0f - (float)(acc[0] / (double)((size_t)NPLANES * IMG * IMG));
}

extern "C" void kernel_launch(void* const* d_in, const int* in_sizes, int n_in,
                              void* d_out, int out_size, void* d_ws, size_t ws_size,
                              hipStream_t stream) {
    const float* img1 = (const float*)d_in[0];
    const float* img2 = (const float*)d_in[1];
    float* out = (float*)d_out;
    double* acc = (double*)d_ws;

    hipMemsetAsync(d_ws, 0, sizeof(double), stream);

    dim3 grid(IMG/TW, IMG/TH, NPLANES);
    ssim_main<<<grid, dim3(256), 0, stream>>>(img1, img2, acc);
    ssim_final<<<1, 1, 0, stream>>>(acc, out);
}

// Round 2
// 203.280 us; speedup vs baseline: 1.7412x; 1.7412x over previous
//
#include <hip/hip_runtime.h>

#define IMG   512
#define TW    64
#define TH    32
#define HALO  5
#define WS    11
#define IHH   (TH + 2*HALO)   // 42 rows of h-smoothed data
#define NP    96
#define NSLOT 256

__global__ __launch_bounds__(256, 3) void ssim_main(const float* __restrict__ img1,
                                                    const float* __restrict__ img2,
                                                    double* __restrict__ acc) {
    __shared__ float hA[5][IHH][TW];   // 53,760 B -> 3 blocks/CU

    const int tid = threadIdx.x;
    const int bx = blockIdx.x;   // 0..7   (x tiles)
    const int by = blockIdx.y;   // 0..15  (y tiles)
    const int plane = blockIdx.z;
    const float* p1 = img1 + (size_t)plane * IMG * IMG;
    const float* p2 = img2 + (size_t)plane * IMG * IMG;

    // Gaussian weights (float32, matches jnp within rounding)
    float w[WS];
    {
        float s = 0.f;
        #pragma unroll
        for (int i = 0; i < WS; ++i) {
            float c = (float)(i - HALO) * (1.0f/1.5f);
            w[i] = expf(-0.5f * c * c);
            s += w[i];
        }
        float inv = 1.0f / s;
        #pragma unroll
        for (int i = 0; i < WS; ++i) w[i] *= inv;
    }

    // ---------------- Phase 1: horizontal conv, global -> registers -> hA ----
    // unit = (row r of padded tile, 8-wide x-chunk ch). 42*8 = 336 units.
    for (int u = tid; u < IHH * 8; u += 256) {
        const int r  = u >> 3;        // 0..41
        const int ch = u & 7;         // 0..7
        const int gy = by * TH + r - HALO;
        const bool rowOK = (unsigned)gy < IMG;

        // registers v[0..23] = image cols (bx*64 + ch*8 - 8) + 0..23
        float v1[24], v2[24];
        #pragma unroll
        for (int j = 0; j < 6; ++j) {
            const int gx = bx * TW + ch * 8 - 8 + 4 * j;
            float4 a = make_float4(0.f, 0.f, 0.f, 0.f);
            float4 b = a;
            if (rowOK && (unsigned)gx < IMG) {
                const float* r1 = p1 + (size_t)gy * IMG + gx;
                const float* r2 = p2 + (size_t)gy * IMG + gx;
                a = *(const float4*)r1;
                b = *(const float4*)r2;
            }
            v1[4*j+0] = a.x; v1[4*j+1] = a.y; v1[4*j+2] = a.z; v1[4*j+3] = a.w;
            v2[4*j+0] = b.x; v2[4*j+1] = b.y; v2[4*j+2] = b.z; v2[4*j+3] = b.w;
        }

        float a1[8], a2[8], a11[8], a22[8], a12[8];
        #pragma unroll
        for (int o = 0; o < 8; ++o) { a1[o]=0.f; a2[o]=0.f; a11[o]=0.f; a22[o]=0.f; a12[o]=0.f; }

        // output o (rel col ch*8+o) uses v[o+3 .. o+13]
        #pragma unroll
        for (int i = 3; i <= 20; ++i) {
            const float x1 = v1[i], x2 = v2[i];
            const float q11 = x1*x1, q22 = x2*x2, q12 = x1*x2;
            #pragma unroll
            for (int o = 0; o < 8; ++o) {
                const int t = i - 3 - o;
                if (t >= 0 && t < WS) {
                    a1[o]  += w[t]*x1;
                    a2[o]  += w[t]*x2;
                    a11[o] += w[t]*q11;
                    a22[o] += w[t]*q22;
                    a12[o] += w[t]*q12;
                }
            }
        }

        float* dst = &hA[0][r][ch*8];
        const int sstr = IHH * TW;    // floats per signal
        *(float4*)(dst + 0*sstr)     = make_float4(a1[0],a1[1],a1[2],a1[3]);
        *(float4*)(dst + 0*sstr + 4) = make_float4(a1[4],a1[5],a1[6],a1[7]);
        *(float4*)(dst + 1*sstr)     = make_float4(a2[0],a2[1],a2[2],a2[3]);
        *(float4*)(dst + 1*sstr + 4) = make_float4(a2[4],a2[5],a2[6],a2[7]);
        *(float4*)(dst + 2*sstr)     = make_float4(a11[0],a11[1],a11[2],a11[3]);
        *(float4*)(dst + 2*sstr + 4) = make_float4(a11[4],a11[5],a11[6],a11[7]);
        *(float4*)(dst + 3*sstr)     = make_float4(a22[0],a22[1],a22[2],a22[3]);
        *(float4*)(dst + 3*sstr + 4) = make_float4(a22[4],a22[5],a22[6],a22[7]);
        *(float4*)(dst + 4*sstr)     = make_float4(a12[0],a12[1],a12[2],a12[3]);
        *(float4*)(dst + 4*sstr + 4) = make_float4(a12[4],a12[5],a12[6],a12[7]);
    }
    __syncthreads();

    // ---------------- Phase 2: vertical conv + SSIM, hA -> registers --------
    // thread = (col c, row-chunk r0). 64*4 = 256 units exactly.
    const float C1 = 0.01f*0.01f, C2 = 0.03f*0.03f;
    float lsum = 0.f;
    {
        const int c  = tid & 63;
        const int r0 = (tid >> 6) << 3;   // 0,8,16,24
        float m1[8], m2[8], m11[8], m22[8], m12[8];
        #pragma unroll
        for (int o = 0; o < 8; ++o) { m1[o]=0.f; m2[o]=0.f; m11[o]=0.f; m22[o]=0.f; m12[o]=0.f; }

        #pragma unroll
        for (int k = 0; k < 18; ++k) {
            const int r = r0 + k;
            const float h1  = hA[0][r][c];
            const float h2  = hA[1][r][c];
            const float h11 = hA[2][r][c];
            const float h22 = hA[3][r][c];
            const float h12 = hA[4][r][c];
            #pragma unroll
            for (int o = 0; o < 8; ++o) {
                const int t = k - o;
                if (t >= 0 && t < WS) {
                    m1[o]  += w[t]*h1;
                    m2[o]  += w[t]*h2;
                    m11[o] += w[t]*h11;
                    m22[o] += w[t]*h22;
                    m12[o] += w[t]*h12;
                }
            }
        }

        #pragma unroll
        for (int o = 0; o < 8; ++o) {
            const float mu1 = m1[o], mu2 = m2[o];
            const float mu1s = mu1*mu1, mu2s = mu2*mu2, mu12 = mu1*mu2;
            const float s11 = m11[o] - mu1s;
            const float s22 = m22[o] - mu2s;
            const float s12 = m12[o] - mu12;
            const float num = (2.f*mu12 + C1) * (2.f*s12 + C2);
            const float den = (mu1s + mu2s + C1) * (s11 + s22 + C2);
            lsum += num / den;
        }
    }

    // wave reduce + block reduce + one spread atomic per block
    #pragma unroll
    for (int d = 32; d >= 1; d >>= 1)
        lsum += __shfl_down(lsum, d, 64);
    __shared__ float wsum[4];
    if ((tid & 63) == 0) wsum[tid >> 6] = lsum;
    __syncthreads();
    if (tid == 0) {
        const float t = wsum[0] + wsum[1] + wsum[2] + wsum[3];
        const int slot = (blockIdx.z * 128 + blockIdx.y * 8 + blockIdx.x) & (NSLOT - 1);
        atomicAdd(&acc[slot], (double)t);
    }
}

__global__ void ssim_final(const double* __restrict__ acc, float* __restrict__ out) {
    const int l = threadIdx.x;   // 64 threads
    double s = acc[l] + acc[l + 64] + acc[l + 128] + acc[l + 192];
    #pragma unroll
    for (int d = 32; d >= 1; d >>= 1)
        s += __shfl_down(s, d, 64);
    if (l == 0)
        out[0] = 1.0f - (float)(s / (double)((size_t)NP * IMG * IMG));
}

extern "C" void kernel_launch(void* const* d_in, const int* in_sizes, int n_in,
                              void* d_out, int out_size, void* d_ws, size_t ws_size,
                              hipStream_t stream) {
    const float* img1 = (const float*)d_in[0];
    const float* img2 = (const float*)d_in[1];
    float* out = (float*)d_out;
    double* acc = (double*)d_ws;

    hipMemsetAsync(d_ws, 0, NSLOT * sizeof(double), stream);

    dim3 grid(IMG / TW, IMG / TH, NP);
    ssim_main<<<grid, dim3(256), 0, stream>>>(img1, img2, acc);
    ssim_final<<<1, dim3(64), 0, stream>>>(acc, out);
}